// Round 4
// baseline (3878.812 us; speedup 1.0000x reference)
//
#include <hip/hip_runtime.h>

#define TT 1024

typedef _Float16 f16;
typedef _Float16 f16x8 __attribute__((ext_vector_type(8)));
typedef float f32x4 __attribute__((ext_vector_type(4)));
typedef unsigned long long u64;

__device__ __forceinline__ float sigmoidf_(float x) { return 1.0f / (1.0f + __expf(-x)); }
__device__ __forceinline__ float tanhf_(float x) { return 1.0f - 2.0f / (__expf(2.0f * x) + 1.0f); }

// ---------------- agent-scope load (proven; memory-side coherent, any placement) ------
__device__ __forceinline__ f16x8 load_frag_agent(const f16* p) {
  union { u64 v[2]; f16x8 f; } u;
  u.v[0] = __hip_atomic_load((u64*)p,     __ATOMIC_RELAXED, __HIP_MEMORY_SCOPE_AGENT);
  u.v[1] = __hip_atomic_load((u64*)p + 1, __ATOMIC_RELAXED, __HIP_MEMORY_SCOPE_AGENT);
  return u.f;
}

// ---------------- XCD-local loads: sc0 (proven for h data in the 3.75ms round) --------
// s_waitcnt vmcnt(0) INSIDE the asm: outputs are complete when the block retires
// (no deferred-wait hazard, rule #18 safe). Frag spacing 32 f16 = 64 B.
__device__ __forceinline__ void load_h8_sc0(const f16* p, f16x8* a) {
  asm volatile(
      "global_load_dwordx4 %0, %8, off sc0\n\t"
      "global_load_dwordx4 %1, %8, off offset:64 sc0\n\t"
      "global_load_dwordx4 %2, %8, off offset:128 sc0\n\t"
      "global_load_dwordx4 %3, %8, off offset:192 sc0\n\t"
      "global_load_dwordx4 %4, %8, off offset:256 sc0\n\t"
      "global_load_dwordx4 %5, %8, off offset:320 sc0\n\t"
      "global_load_dwordx4 %6, %8, off offset:384 sc0\n\t"
      "global_load_dwordx4 %7, %8, off offset:448 sc0\n\t"
      "s_waitcnt vmcnt(0)"
      : "=&v"(a[0]), "=&v"(a[1]), "=&v"(a[2]), "=&v"(a[3]),
        "=&v"(a[4]), "=&v"(a[5]), "=&v"(a[6]), "=&v"(a[7])
      : "v"(p)
      : "memory");
}
__device__ __forceinline__ void load_h16_sc0(const f16* p0, const f16* p1, f16x8* a) {
  asm volatile(
      "global_load_dwordx4 %0, %16, off sc0\n\t"
      "global_load_dwordx4 %1, %16, off offset:64 sc0\n\t"
      "global_load_dwordx4 %2, %16, off offset:128 sc0\n\t"
      "global_load_dwordx4 %3, %16, off offset:192 sc0\n\t"
      "global_load_dwordx4 %4, %16, off offset:256 sc0\n\t"
      "global_load_dwordx4 %5, %16, off offset:320 sc0\n\t"
      "global_load_dwordx4 %6, %16, off offset:384 sc0\n\t"
      "global_load_dwordx4 %7, %16, off offset:448 sc0\n\t"
      "global_load_dwordx4 %8, %17, off sc0\n\t"
      "global_load_dwordx4 %9, %17, off offset:64 sc0\n\t"
      "global_load_dwordx4 %10, %17, off offset:128 sc0\n\t"
      "global_load_dwordx4 %11, %17, off offset:192 sc0\n\t"
      "global_load_dwordx4 %12, %17, off offset:256 sc0\n\t"
      "global_load_dwordx4 %13, %17, off offset:320 sc0\n\t"
      "global_load_dwordx4 %14, %17, off offset:384 sc0\n\t"
      "global_load_dwordx4 %15, %17, off offset:448 sc0\n\t"
      "s_waitcnt vmcnt(0)"
      : "=&v"(a[0]), "=&v"(a[1]), "=&v"(a[2]), "=&v"(a[3]),
        "=&v"(a[4]), "=&v"(a[5]), "=&v"(a[6]), "=&v"(a[7]),
        "=&v"(a[8]), "=&v"(a[9]), "=&v"(a[10]), "=&v"(a[11]),
        "=&v"(a[12]), "=&v"(a[13]), "=&v"(a[14]), "=&v"(a[15])
      : "v"(p0), "v"(p1)
      : "memory");
}
// single sc0 dword sample (fast-path poll; value is monotonic so staleness is SAFE)
__device__ __forceinline__ unsigned load_u32_sc0(const unsigned* p) {
  unsigned v;
  asm volatile("global_load_dword %0, %1, off sc0\n\t"
               "s_waitcnt vmcnt(0)"
               : "=&v"(v) : "v"(p) : "memory");
  return v;
}

// Group barrier over 32 WGs. Flag STORES are agent-scope in BOTH modes (proven).
// LOCAL poll: sc0 fast samples with a guaranteed-progress agent load every 4th
// iteration. Flags are monotonic and the predicate is v>=e, so a stale sc0 read is
// always <= truth -> can NEVER release early; the agent load bounds liveness ->
// can never hang. Worst case == proven round-2 behavior; best case ~300cy sampling.
// !LOCAL: bit-identical proven agent-scope barrier (with sleep).
template <bool LOCAL>
__device__ __forceinline__ void group_barrier(unsigned* slots, int role, unsigned e, int tid) {
  __syncthreads();
  __atomic_signal_fence(__ATOMIC_SEQ_CST);
  if (tid == 0)
    __hip_atomic_store(slots + role * 64, e, __ATOMIC_RELAXED, __HIP_MEMORY_SCOPE_AGENT);
  if (tid < 64) {
    const unsigned* sp = slots + (tid & 31) * 64;
    if constexpr (LOCAL) {
      for (int k = 0;; ++k) {
        unsigned v = ((k & 3) == 3)
                         ? __hip_atomic_load(sp, __ATOMIC_RELAXED, __HIP_MEMORY_SCOPE_AGENT)
                         : load_u32_sc0(sp);
        if (__all(v >= e)) break;
      }
    } else {
      for (;;) {
        unsigned v = __hip_atomic_load(sp, __ATOMIC_RELAXED, __HIP_MEMORY_SCOPE_AGENT);
        if (__all(v >= e)) break;
        __builtin_amdgcn_s_sleep(2);
      }
    }
  }
  __atomic_signal_fence(__ATOMIC_SEQ_CST);
  __syncthreads();
}

// One LSTM layer's persistent loop. Geometry: 8 groups x (16 L0-WG + 16 L1-WG);
// each group owns 32 batch rows (closed over batch => h never leaves the group);
// each WG owns 16 hidden units. Per wave (rw=wave&1 row-block, uw=wave>>1
// unit-block): same MFMA micro-structure as the verified baseline (i/f in bA,
// g/o in bB, C/D col=lane&15, row=(lane>>4)*4+reg).
// LOCAL: group fully on one XCD -> h via plain stores + sc0 loads (proven) and the
// fast-sample barrier. !LOCAL: byte-identical proven agent path.
template <int LAYER, bool LOCAL>
__device__ void run_layer(const float* __restrict__ xin, const f16* __restrict__ in2base,
                          const float* __restrict__ Wih, const float* __restrict__ Whh,
                          const float* __restrict__ bias, f16* __restrict__ hself,
                          unsigned* slots, int role, int ng, int b0r,
                          float (*Gs)[68], int tid) {
  constexpr int NCH = (LAYER == 0) ? 12 : 16;
  constexpr int DIN = (LAYER == 0) ? 128 : 256;
  constexpr int HCH = NCH / 2;

  const int lane = tid & 63, wave = tid >> 6;
  const int q = lane >> 4, mm = lane & 15;
  const int rw = wave & 1, uw = wave >> 1;
  const int u0 = ng * 16 + uw * 8;

  // epilogue mapping: each thread owns 1 batch row x 2 adjacent units (4B store)
  const int up_e = tid & 7, bl_e = tid >> 3;          // unit pair 0..7, batch row 0..31
  const int uwe = up_e >> 2, ppe = up_e & 3;
  const int uc0 = ng * 16 + uwe * 8 + 2 * ppe, uc1 = uc0 + 1;
  const int gcol = uwe * 32 + 2 * ppe;                // col of gate i in Gs
  const float bi0 = bias[uc0],       bi1 = bias[uc1];
  const float bf0 = bias[256 + uc0], bf1 = bias[256 + uc1];
  const float bg0 = bias[512 + uc0], bg1 = bias[512 + uc1];
  const float bo0 = bias[768 + uc0], bo1 = bias[768 + uc1];

  // B-fragment preload: B[k=(lane>>4)*8+j][n=lane&15], W row = gate*256 + unit
  const int row0 = ((mm >> 3)) * 256 + u0 + (mm & 7);      // gates i,f
  const int row1 = ((mm >> 3) + 2) * 256 + u0 + (mm & 7);  // gates g,o
  f16x8 bA[NCH], bB[NCH];
#pragma unroll
  for (int c = 0; c < NCH; ++c) {
    const int k0 = c * 32 + q * 8;
    const float* s0 = (c < 8) ? (Whh + row0 * 256 + k0) : (Wih + row0 * DIN + (k0 - 256));
    const float* s1 = (c < 8) ? (Whh + row1 * 256 + k0) : (Wih + row1 * DIN + (k0 - 256));
    f16x8 v0, v1;
#pragma unroll
    for (int j = 0; j < 8; ++j) { v0[j] = (f16)s0[j]; v1[j] = (f16)s1[j]; }
    bA[c] = v0; bB[c] = v1;
  }

  float cA = 0.f, cB = 0.f;  // cell state for the 2 owned units, registers
  const int brow = b0r + rw * 16 + mm;

  float4 axr[8];   // raw fp32 x for the NEXT step (loaded 1 iter ahead)
  f16x8 ax[4];     // fp16 x fragments for the CURRENT step

  for (int it = 0; it <= TT + 1; ++it) {
    const int i = it - 1;
    const bool active = (LAYER == 0) ? (i >= 0 && i < TT) : (i >= 1 && i <= TT);

    if (LAYER == 0 && active) {
      // convert last iteration's raw x (drained at the intervening barrier)
#pragma unroll
      for (int c = 0; c < 4; ++c) {
        const float4 fa = axr[2 * c], fb = axr[2 * c + 1];
        f16x8 v; v[0]=(f16)fa.x; v[1]=(f16)fa.y; v[2]=(f16)fa.z; v[3]=(f16)fa.w;
        v[4]=(f16)fb.x; v[5]=(f16)fb.y; v[6]=(f16)fb.z; v[7]=(f16)fb.w;
        ax[c] = v;
      }
    }

    f16x8 a[NCH];
    if (active) {
      const f16* hprev = hself + ((i + 1) & 1) * 65536;
      const f16* pa1 = hprev + brow * 256 + q * 8;
      if (LAYER == 0) {
        if constexpr (LOCAL) load_h8_sc0(pa1, a);
        else {
#pragma unroll
          for (int c = 0; c < 8; ++c) a[c] = load_frag_agent(pa1 + c * 32);
        }
#pragma unroll
        for (int c = 8; c < NCH; ++c) a[c] = ax[c - 8];
      } else {
        const f16* pa2 = in2base + ((i + 1) & 1) * 65536 + brow * 256 + q * 8;
        if constexpr (LOCAL) load_h16_sc0(pa1, pa2, a);
        else {
#pragma unroll
          for (int c = 0; c < 8; ++c) a[c] = load_frag_agent(pa1 + c * 32);
#pragma unroll
          for (int c = 8; c < NCH; ++c) a[c] = load_frag_agent(pa2 + (c - 8) * 32);
        }
      }
    }

    // issue raw x loads for step `it` (consumed next iteration); issued AFTER the
    // h-load wait so they stay in flight across MFMA/epilogue/barrier.
    if (LAYER == 0 && it < TT) {
      const float* px = xin + (brow * 1024 + it) * 128 + q * 8;
#pragma unroll
      for (int c = 0; c < 4; ++c) {
        axr[2 * c]     = *(const float4*)(px + c * 32);
        axr[2 * c + 1] = *(const float4*)(px + c * 32 + 4);
      }
    }

    if (active) {
      // 4 independent accumulation chains (2 per gate-pair) -> hides MFMA dependent
      // latency on this 1-wave/SIMD kernel; summed once at the end.
      f32x4 p0 = {0.f, 0.f, 0.f, 0.f}, p1 = {0.f, 0.f, 0.f, 0.f};
      f32x4 r0 = {0.f, 0.f, 0.f, 0.f}, r1 = {0.f, 0.f, 0.f, 0.f};
#pragma unroll
      for (int c = 0; c < HCH; ++c) {
        p0 = __builtin_amdgcn_mfma_f32_16x16x32_f16(a[c], bA[c], p0, 0, 0, 0);
        p1 = __builtin_amdgcn_mfma_f32_16x16x32_f16(a[c], bB[c], p1, 0, 0, 0);
        r0 = __builtin_amdgcn_mfma_f32_16x16x32_f16(a[HCH + c], bA[HCH + c], r0, 0, 0, 0);
        r1 = __builtin_amdgcn_mfma_f32_16x16x32_f16(a[HCH + c], bB[HCH + c], r1, 0, 0, 0);
      }
      const f32x4 acc0 = p0 + r0, acc1 = p1 + r1;
      // C/D layout: col=lane&15 (gate unit), row=(lane>>4)*4+reg (batch)
      // Gs stride 68: epilogue reads 2-way (free), writes <=2-way (was 4-way at 66).
#pragma unroll
      for (int r = 0; r < 4; ++r) {
        Gs[rw * 16 + q * 4 + r][uw * 32 + mm] = acc0[r];
        Gs[rw * 16 + q * 4 + r][uw * 32 + 16 + mm] = acc1[r];
      }
      __syncthreads();
      {
        f16* hout = hself + (i & 1) * 65536;
        const float gi0 = Gs[bl_e][gcol]      + bi0, gi1 = Gs[bl_e][gcol + 1]  + bi1;
        const float gf0 = Gs[bl_e][gcol + 8]  + bf0, gf1 = Gs[bl_e][gcol + 9]  + bf1;
        const float gg0 = Gs[bl_e][gcol + 16] + bg0, gg1 = Gs[bl_e][gcol + 17] + bg1;
        const float go0 = Gs[bl_e][gcol + 24] + bo0, go1 = Gs[bl_e][gcol + 25] + bo1;
        cA = sigmoidf_(gf0) * cA + sigmoidf_(gi0) * tanhf_(gg0);
        cB = sigmoidf_(gf1) * cB + sigmoidf_(gi1) * tanhf_(gg1);
        union { f16 h2v[2]; unsigned u; } pk;
        pk.h2v[0] = (f16)(sigmoidf_(go0) * tanhf_(cA));
        pk.h2v[1] = (f16)(sigmoidf_(go1) * tanhf_(cB));
        unsigned* dst = (unsigned*)(hout + (b0r + bl_e) * 256 + uc0);
        if constexpr (LOCAL) {
          // plain write-through store: lands in own-XCD L2; drained (vmcnt 0) by the
          // barrier's __syncthreads BEFORE the flag store => release-ordered. (proven)
          *dst = pk.u;
        } else {
          __hip_atomic_store(dst, pk.u, __ATOMIC_RELAXED, __HIP_MEMORY_SCOPE_AGENT);
        }
      }
    }

    if (it <= TT) group_barrier<LOCAL>(slots, role, (unsigned)(it + 1), tid);
  }
}

__global__ __launch_bounds__(256, 1) void lstm_persistent(
    const float* __restrict__ x,
    const float* __restrict__ Wih0, const float* __restrict__ Whh0, const float* __restrict__ b0v,
    const float* __restrict__ Wih1, const float* __restrict__ Whh1, const float* __restrict__ b1v,
    f16* h1buf, f16* h2buf, unsigned* F) {
  __shared__ float Gs[32][68];
  __shared__ int sh[3];
  const int tid = threadIdx.x;

  // ---- XCD self-organization. NG (9 u32) lives at F[32..40]: padding inside group-0
  // slot 0 (flags sit at multiples of 64 u32), zeroed by the slot memset.
  if (tid == 0) {
    // HW_REG_XCC_ID = hwreg id 20, offset 0, size 32 -> imm = 20 | (31<<11) = 63508
    unsigned xcc = __builtin_amdgcn_s_getreg(63508) & 7u;
    unsigned* NG = F + 32;
    unsigned rank = __hip_atomic_fetch_add(&NG[xcc], 1u, __ATOMIC_RELAXED, __HIP_MEMORY_SCOPE_AGENT);
    __hip_atomic_fetch_add(&NG[8], 1u, __ATOMIC_RELEASE, __HIP_MEMORY_SCOPE_AGENT);
    while (__hip_atomic_load(&NG[8], __ATOMIC_ACQUIRE, __HIP_MEMORY_SCOPE_AGENT) < 256u)
      __builtin_amdgcn_s_sleep(8);
    unsigned cnt[8];
#pragma unroll
    for (int xx = 0; xx < 8; ++xx)
      cnt[xx] = __hip_atomic_load(&NG[xx], __ATOMIC_RELAXED, __HIP_MEMORY_SCOPE_AGENT);
    int group, role2;
    if (rank < 32u) {
      group = (int)xcc; role2 = (int)rank;
    } else {
      // deterministic overflow assignment: my overflow index -> j-th deficit slot
      int ov = (int)rank - 32;
      for (int xx = 0; xx < (int)xcc; ++xx) ov += max(0, (int)cnt[xx] - 32);
      int gg = 0, acc = 0;
      for (gg = 0; gg < 8; ++gg) {
        const int d = 32 - min(32, (int)cnt[gg]);
        if (ov < acc + d) break;
        acc += d;
      }
      if (gg > 7) gg = 7;
      group = gg; role2 = min(31, (int)cnt[gg] + (ov - acc));
    }
    sh[0] = group; sh[1] = role2; sh[2] = (cnt[group] >= 32u) ? 1 : 0;  // fully local?
  }
  __syncthreads();
  const int group = sh[0], role = sh[1], local = sh[2];
  unsigned* slots = F + group * 2048;   // 32 slots x 64 u32 (256B apart) per group
  const int b0r = group * 32;
  const int layer = role >> 4, ng = role & 15;

  if (layer == 0) {
    if (local) run_layer<0, true >(x, nullptr, Wih0, Whh0, b0v, h1buf, slots, role, ng, b0r, Gs, tid);
    else       run_layer<0, false>(x, nullptr, Wih0, Whh0, b0v, h1buf, slots, role, ng, b0r, Gs, tid);
  } else {
    if (local) run_layer<1, true >(nullptr, h1buf, Wih1, Whh1, b1v, h2buf, slots, role, ng, b0r, Gs, tid);
    else       run_layer<1, false>(nullptr, h1buf, Wih1, Whh1, b1v, h2buf, slots, role, ng, b0r, Gs, tid);
  }
}

// final dense (C=10) + softmax on h2[T-1]; one wave per batch row.
// (kernel-end release flushes dirty h lines; standard inter-kernel visibility.)
__global__ __launch_bounds__(64, 1) void dense_softmax_k(const f16* __restrict__ h2,
                                                         const float* __restrict__ Wd,
                                                         const float* __restrict__ bd,
                                                         float* __restrict__ out) {
  const int b = blockIdx.x, lane = threadIdx.x;
  float hv[4];
#pragma unroll
  for (int j = 0; j < 4; ++j) hv[j] = (float)h2[b * 256 + lane + 64 * j];
  float p[10];
#pragma unroll
  for (int c = 0; c < 10; ++c) {
    float s = 0.f;
#pragma unroll
    for (int j = 0; j < 4; ++j) s += hv[j] * Wd[c * 256 + lane + 64 * j];
#pragma unroll
    for (int off = 32; off >= 1; off >>= 1) s += __shfl_xor(s, off, 64);
    p[c] = s;
  }
  if (lane == 0) {
    float mx = -1e30f;
#pragma unroll
    for (int c = 0; c < 10; ++c) { p[c] += bd[c]; mx = fmaxf(mx, p[c]); }
    float den = 0.f;
#pragma unroll
    for (int c = 0; c < 10; ++c) { p[c] = __expf(p[c] - mx); den += p[c]; }
#pragma unroll
    for (int c = 0; c < 10; ++c) out[b * 10 + c] = p[c] / den;
  }
}

extern "C" void kernel_launch(void* const* d_in, const int* in_sizes, int n_in,
                              void* d_out, int out_size, void* d_ws, size_t ws_size,
                              hipStream_t stream) {
  const float* x    = (const float*)d_in[0];
  const float* Wih0 = (const float*)d_in[1];
  const float* Whh0 = (const float*)d_in[2];
  const float* b0v  = (const float*)d_in[3];
  const float* Wih1 = (const float*)d_in[4];
  const float* Whh1 = (const float*)d_in[5];
  const float* b1v  = (const float*)d_in[6];
  const float* Wd   = (const float*)d_in[7];
  const float* bd   = (const float*)d_in[8];

  char* ws = (char*)d_ws;
  // layout: h1buf[2] @0 (256KB) | h2buf[2] @256K (256KB) | slots+NG @512K (64KB)
  f16* h1buf = (f16*)(ws);
  f16* h2buf = (f16*)(ws + 256 * 1024);
  unsigned* F = (unsigned*)(ws + 512 * 1024);

  // zero h1buf[1] + h2buf[0] (initial hidden states, contiguous) and all slots/NG
  hipMemsetAsync(ws + 128 * 1024, 0, 256 * 1024, stream);
  hipMemsetAsync(ws + 512 * 1024, 0, 64 * 1024, stream);

  lstm_persistent<<<256, 256, 0, stream>>>(x, Wih0, Whh0, b0v, Wih1, Whh1, b1v,
                                           h1buf, h2buf, F);
  // h2[T-1] lands in h2buf[0] (T even)
  dense_softmax_k<<<256, 64, 0, stream>>>(h2buf, Wd, bd, (float*)d_out);
}

// Round 6
// 3713.864 us; speedup vs baseline: 1.0444x; 1.0444x over previous
//
#include <hip/hip_runtime.h>

#define TT 1024

typedef _Float16 f16;
typedef _Float16 f16x8 __attribute__((ext_vector_type(8)));
typedef float f32x4 __attribute__((ext_vector_type(4)));
typedef unsigned long long u64;

__device__ __forceinline__ float sigmoidf_(float x) { return 1.0f / (1.0f + __expf(-x)); }
__device__ __forceinline__ float tanhf_(float x) { return 1.0f - 2.0f / (__expf(2.0f * x) + 1.0f); }

// ---------------- agent-scope load (proven; memory-side coherent, any placement) ------
__device__ __forceinline__ f16x8 load_frag_agent(const f16* p) {
  union { u64 v[2]; f16x8 f; } u;
  u.v[0] = __hip_atomic_load((u64*)p,     __ATOMIC_RELAXED, __HIP_MEMORY_SCOPE_AGENT);
  u.v[1] = __hip_atomic_load((u64*)p + 1, __ATOMIC_RELAXED, __HIP_MEMORY_SCOPE_AGENT);
  return u.f;
}

// ---------------- XCD-local loads: sc0 (proven for h data since the 3.75ms round) -----
// s_waitcnt vmcnt(0) INSIDE the asm: outputs are complete when the block retires
// (no deferred-wait hazard, rule #18 safe). Frag spacing 32 f16 = 64 B.
__device__ __forceinline__ void load_h8_sc0(const f16* p, f16x8* a) {
  asm volatile(
      "global_load_dwordx4 %0, %8, off sc0\n\t"
      "global_load_dwordx4 %1, %8, off offset:64 sc0\n\t"
      "global_load_dwordx4 %2, %8, off offset:128 sc0\n\t"
      "global_load_dwordx4 %3, %8, off offset:192 sc0\n\t"
      "global_load_dwordx4 %4, %8, off offset:256 sc0\n\t"
      "global_load_dwordx4 %5, %8, off offset:320 sc0\n\t"
      "global_load_dwordx4 %6, %8, off offset:384 sc0\n\t"
      "global_load_dwordx4 %7, %8, off offset:448 sc0\n\t"
      "s_waitcnt vmcnt(0)"
      : "=&v"(a[0]), "=&v"(a[1]), "=&v"(a[2]), "=&v"(a[3]),
        "=&v"(a[4]), "=&v"(a[5]), "=&v"(a[6]), "=&v"(a[7])
      : "v"(p)
      : "memory");
}
__device__ __forceinline__ void load_h16_sc0(const f16* p0, const f16* p1, f16x8* a) {
  asm volatile(
      "global_load_dwordx4 %0, %16, off sc0\n\t"
      "global_load_dwordx4 %1, %16, off offset:64 sc0\n\t"
      "global_load_dwordx4 %2, %16, off offset:128 sc0\n\t"
      "global_load_dwordx4 %3, %16, off offset:192 sc0\n\t"
      "global_load_dwordx4 %4, %16, off offset:256 sc0\n\t"
      "global_load_dwordx4 %5, %16, off offset:320 sc0\n\t"
      "global_load_dwordx4 %6, %16, off offset:384 sc0\n\t"
      "global_load_dwordx4 %7, %16, off offset:448 sc0\n\t"
      "global_load_dwordx4 %8, %17, off sc0\n\t"
      "global_load_dwordx4 %9, %17, off offset:64 sc0\n\t"
      "global_load_dwordx4 %10, %17, off offset:128 sc0\n\t"
      "global_load_dwordx4 %11, %17, off offset:192 sc0\n\t"
      "global_load_dwordx4 %12, %17, off offset:256 sc0\n\t"
      "global_load_dwordx4 %13, %17, off offset:320 sc0\n\t"
      "global_load_dwordx4 %14, %17, off offset:384 sc0\n\t"
      "global_load_dwordx4 %15, %17, off offset:448 sc0\n\t"
      "s_waitcnt vmcnt(0)"
      : "=&v"(a[0]), "=&v"(a[1]), "=&v"(a[2]), "=&v"(a[3]),
        "=&v"(a[4]), "=&v"(a[5]), "=&v"(a[6]), "=&v"(a[7]),
        "=&v"(a[8]), "=&v"(a[9]), "=&v"(a[10]), "=&v"(a[11]),
        "=&v"(a[12]), "=&v"(a[13]), "=&v"(a[14]), "=&v"(a[15])
      : "v"(p0), "v"(p1)
      : "memory");
}

// Relaxed-lockstep group barrier. Mechanics are BIT-IDENTICAL to the proven r2 barrier
// (agent store arrive, agent load poll, sleep(2)); only the per-slot THRESHOLD differs:
//   L0 WGs: L0 slots (0..15) >= e,   L1 slots (16..31) >= e-1   (h1 is 3-buffered:
//           L0 writing h1[it-1] evicts h1[it-4], last read by L1 at iter it-2 ->
//           L1 posted >= e-1 is exactly the overwrite gate)
//   L1 WGs: all 32 slots >= e (needs L0's h1[it-2] and L1 peers' h2)
// Deadlock-free: arrive precedes poll (a blocked WG has posted its epoch); for any
// L0/L1 lag, one side's predicate is satisfied -> global progress. Flags monotonic.
template <int LAYER>
__device__ __forceinline__ void group_barrier(unsigned* slots, int role, unsigned e, int tid) {
  __syncthreads();
  __atomic_signal_fence(__ATOMIC_SEQ_CST);
  if (tid == 0)
    __hip_atomic_store(slots + role * 64, e, __ATOMIC_RELAXED, __HIP_MEMORY_SCOPE_AGENT);
  if (tid < 64) {
    const int s = tid & 31;
    const unsigned thr = (LAYER == 0 && s >= 16) ? e - 1u : e;
    for (;;) {
      unsigned v = __hip_atomic_load(slots + s * 64, __ATOMIC_RELAXED,
                                     __HIP_MEMORY_SCOPE_AGENT);
      if (__all(v >= thr)) break;
      __builtin_amdgcn_s_sleep(2);
    }
  }
  __atomic_signal_fence(__ATOMIC_SEQ_CST);
  __syncthreads();
}

// One LSTM layer's persistent loop. Geometry: 8 groups x (16 L0-WG + 16 L1-WG);
// each group owns 32 batch rows (closed over batch => h never leaves the group);
// each WG owns 16 hidden units. Per wave (rw=wave&1 row-block, uw=wave>>1
// unit-block): same MFMA micro-structure as the verified baseline (i/f in bA,
// g/o in bB, C/D col=lane&15, row=(lane>>4)*4+reg).
// h1 is TRIPLE-buffered (write buf i%3, read buf (i-1)%3 == (i+2)%3) to give L0 one
// step of slack over L1. h2 stays double-buffered (tight within L1).
// LOCAL: group fully on one XCD -> h via plain stores + sc0 loads (proven).
// !LOCAL: byte-identical proven agent data path.
template <int LAYER, bool LOCAL>
__device__ void run_layer(const float* __restrict__ xin, const f16* __restrict__ in2base,
                          const float* __restrict__ Wih, const float* __restrict__ Whh,
                          const float* __restrict__ bias, f16* __restrict__ hself,
                          unsigned* slots, int role, int ng, int b0r,
                          float (*Gs)[68], int tid) {
  constexpr int NCH = (LAYER == 0) ? 12 : 16;
  constexpr int DIN = (LAYER == 0) ? 128 : 256;

  const int lane = tid & 63, wave = tid >> 6;
  const int q = lane >> 4, mm = lane & 15;
  const int rw = wave & 1, uw = wave >> 1;
  const int u0 = ng * 16 + uw * 8;

  // epilogue mapping: each thread owns 1 batch row x 2 adjacent units (4B store)
  const int up_e = tid & 7, bl_e = tid >> 3;          // unit pair 0..7, batch row 0..31
  const int uwe = up_e >> 2, ppe = up_e & 3;
  const int uc0 = ng * 16 + uwe * 8 + 2 * ppe, uc1 = uc0 + 1;
  const int gcol = uwe * 32 + 2 * ppe;                // col of gate i in Gs
  const float bi0 = bias[uc0],       bi1 = bias[uc1];
  const float bf0 = bias[256 + uc0], bf1 = bias[256 + uc1];
  const float bg0 = bias[512 + uc0], bg1 = bias[512 + uc1];
  const float bo0 = bias[768 + uc0], bo1 = bias[768 + uc1];

  // B-fragment preload: B[k=(lane>>4)*8+j][n=lane&15], W row = gate*256 + unit
  const int row0 = ((mm >> 3)) * 256 + u0 + (mm & 7);      // gates i,f
  const int row1 = ((mm >> 3) + 2) * 256 + u0 + (mm & 7);  // gates g,o
  f16x8 bA[NCH], bB[NCH];
#pragma unroll
  for (int c = 0; c < NCH; ++c) {
    const int k0 = c * 32 + q * 8;
    const float* s0 = (c < 8) ? (Whh + row0 * 256 + k0) : (Wih + row0 * DIN + (k0 - 256));
    const float* s1 = (c < 8) ? (Whh + row1 * 256 + k0) : (Wih + row1 * DIN + (k0 - 256));
    f16x8 v0, v1;
#pragma unroll
    for (int j = 0; j < 8; ++j) { v0[j] = (f16)s0[j]; v1[j] = (f16)s1[j]; }
    bA[c] = v0; bB[c] = v1;
  }

  float cA = 0.f, cB = 0.f;  // cell state for the 2 owned units, registers
  const int brow = b0r + rw * 16 + mm;

  float4 axr[8];   // raw fp32 x for the NEXT step (loaded 1 iter ahead)
  f16x8 ax[4];     // fp16 x fragments for the CURRENT step

  for (int it = 0; it <= TT + 1; ++it) {
    const int i = it - 1;
    const bool active = (LAYER == 0) ? (i >= 0 && i < TT) : (i >= 1 && i <= TT);

    if (LAYER == 0 && active) {
      // convert last iteration's raw x (drained at the intervening barrier)
#pragma unroll
      for (int c = 0; c < 4; ++c) {
        const float4 fa = axr[2 * c], fb = axr[2 * c + 1];
        f16x8 v; v[0]=(f16)fa.x; v[1]=(f16)fa.y; v[2]=(f16)fa.z; v[3]=(f16)fa.w;
        v[4]=(f16)fb.x; v[5]=(f16)fb.y; v[6]=(f16)fb.z; v[7]=(f16)fb.w;
        ax[c] = v;
      }
    }

    f16x8 a[NCH];
    if (active) {
      // L0: own h1, 3-buffer, read (i-1)%3 == (i+2)%3.  L1: own h2, 2-buffer.
      const f16* hprev = (LAYER == 0) ? (hself + ((i + 2) % 3) * 65536)
                                      : (hself + ((i + 1) & 1) * 65536);
      const f16* pa1 = hprev + brow * 256 + q * 8;
      if (LAYER == 0) {
        if constexpr (LOCAL) load_h8_sc0(pa1, a);
        else {
#pragma unroll
          for (int c = 0; c < 8; ++c) a[c] = load_frag_agent(pa1 + c * 32);
        }
#pragma unroll
        for (int c = 8; c < NCH; ++c) a[c] = ax[c - 8];
      } else {
        // L1 input = h1[i-1], 3-buffer read (i-1)%3 == (i+2)%3
        const f16* pa2 = in2base + ((i + 2) % 3) * 65536 + brow * 256 + q * 8;
        if constexpr (LOCAL) load_h16_sc0(pa1, pa2, a);
        else {
#pragma unroll
          for (int c = 0; c < 8; ++c) a[c] = load_frag_agent(pa1 + c * 32);
#pragma unroll
          for (int c = 8; c < NCH; ++c) a[c] = load_frag_agent(pa2 + (c - 8) * 32);
        }
      }
    }

    // issue raw x loads for step `it` (consumed next iteration); issued AFTER the
    // h-load wait so they stay in flight across MFMA/epilogue/barrier.
    if (LAYER == 0 && it < TT) {
      const float* px = xin + (brow * 1024 + it) * 128 + q * 8;
#pragma unroll
      for (int c = 0; c < 4; ++c) {
        axr[2 * c]     = *(const float4*)(px + c * 32);
        axr[2 * c + 1] = *(const float4*)(px + c * 32 + 4);
      }
    }

    if (active) {
      f32x4 acc0 = {0.f, 0.f, 0.f, 0.f}, acc1 = {0.f, 0.f, 0.f, 0.f};
#pragma unroll
      for (int c = 0; c < NCH; ++c) {
        acc0 = __builtin_amdgcn_mfma_f32_16x16x32_f16(a[c], bA[c], acc0, 0, 0, 0);
        acc1 = __builtin_amdgcn_mfma_f32_16x16x32_f16(a[c], bB[c], acc1, 0, 0, 0);
      }
      // C/D layout: col=lane&15 (gate unit), row=(lane>>4)*4+reg (batch)
      // Gs stride 68: epilogue reads 2-way (free), writes <=2-way (was 4-way at 66).
#pragma unroll
      for (int r = 0; r < 4; ++r) {
        Gs[rw * 16 + q * 4 + r][uw * 32 + mm] = acc0[r];
        Gs[rw * 16 + q * 4 + r][uw * 32 + 16 + mm] = acc1[r];
      }
      __syncthreads();
      {
        f16* hout = (LAYER == 0) ? (hself + (i % 3) * 65536)
                                 : (hself + (i & 1) * 65536);
        const float gi0 = Gs[bl_e][gcol]      + bi0, gi1 = Gs[bl_e][gcol + 1]  + bi1;
        const float gf0 = Gs[bl_e][gcol + 8]  + bf0, gf1 = Gs[bl_e][gcol + 9]  + bf1;
        const float gg0 = Gs[bl_e][gcol + 16] + bg0, gg1 = Gs[bl_e][gcol + 17] + bg1;
        const float go0 = Gs[bl_e][gcol + 24] + bo0, go1 = Gs[bl_e][gcol + 25] + bo1;
        cA = sigmoidf_(gf0) * cA + sigmoidf_(gi0) * tanhf_(gg0);
        cB = sigmoidf_(gf1) * cB + sigmoidf_(gi1) * tanhf_(gg1);
        union { f16 h2v[2]; unsigned u; } pk;
        pk.h2v[0] = (f16)(sigmoidf_(go0) * tanhf_(cA));
        pk.h2v[1] = (f16)(sigmoidf_(go1) * tanhf_(cB));
        unsigned* dst = (unsigned*)(hout + (b0r + bl_e) * 256 + uc0);
        if constexpr (LOCAL) {
          // plain write-through store: lands in own-XCD L2; drained (vmcnt 0) by the
          // barrier's __syncthreads BEFORE the agent flag store => release-ordered.
          *dst = pk.u;
        } else {
          __hip_atomic_store(dst, pk.u, __ATOMIC_RELAXED, __HIP_MEMORY_SCOPE_AGENT);
        }
      }
    }

    if (it <= TT) group_barrier<LAYER>(slots, role, (unsigned)(it + 1), tid);
  }
}

__global__ __launch_bounds__(256, 1) void lstm_persistent(
    const float* __restrict__ x,
    const float* __restrict__ Wih0, const float* __restrict__ Whh0, const float* __restrict__ b0v,
    const float* __restrict__ Wih1, const float* __restrict__ Whh1, const float* __restrict__ b1v,
    f16* h1buf, f16* h2buf, unsigned* F) {
  __shared__ float Gs[32][68];
  __shared__ int sh[3];
  const int tid = threadIdx.x;

  // ---- XCD self-organization (proven r2/r4). NG (9 u32) at F[32..40]: padding inside
  // group-0 slot 0 (flags at multiples of 64 u32), zeroed by the slot memset.
  if (tid == 0) {
    // HW_REG_XCC_ID = hwreg id 20, offset 0, size 32 -> imm = 20 | (31<<11) = 63508
    unsigned xcc = __builtin_amdgcn_s_getreg(63508) & 7u;
    unsigned* NG = F + 32;
    unsigned rank = __hip_atomic_fetch_add(&NG[xcc], 1u, __ATOMIC_RELAXED, __HIP_MEMORY_SCOPE_AGENT);
    __hip_atomic_fetch_add(&NG[8], 1u, __ATOMIC_RELEASE, __HIP_MEMORY_SCOPE_AGENT);
    while (__hip_atomic_load(&NG[8], __ATOMIC_ACQUIRE, __HIP_MEMORY_SCOPE_AGENT) < 256u)
      __builtin_amdgcn_s_sleep(8);
    unsigned cnt[8];
#pragma unroll
    for (int xx = 0; xx < 8; ++xx)
      cnt[xx] = __hip_atomic_load(&NG[xx], __ATOMIC_RELAXED, __HIP_MEMORY_SCOPE_AGENT);
    int group, role2;
    if (rank < 32u) {
      group = (int)xcc; role2 = (int)rank;
    } else {
      // deterministic overflow assignment: my overflow index -> j-th deficit slot
      int ov = (int)rank - 32;
      for (int xx = 0; xx < (int)xcc; ++xx) ov += max(0, (int)cnt[xx] - 32);
      int gg = 0, acc = 0;
      for (gg = 0; gg < 8; ++gg) {
        const int d = 32 - min(32, (int)cnt[gg]);
        if (ov < acc + d) break;
        acc += d;
      }
      if (gg > 7) gg = 7;
      group = gg; role2 = min(31, (int)cnt[gg] + (ov - acc));
    }
    sh[0] = group; sh[1] = role2; sh[2] = (cnt[group] >= 32u) ? 1 : 0;  // fully local?
  }
  __syncthreads();
  const int group = sh[0], role = sh[1], local = sh[2];
  unsigned* slots = F + group * 2048;   // 32 slots x 64 u32 (256B apart) per group
  const int b0r = group * 32;
  const int layer = role >> 4, ng = role & 15;

  if (layer == 0) {
    if (local) run_layer<0, true >(x, nullptr, Wih0, Whh0, b0v, h1buf, slots, role, ng, b0r, Gs, tid);
    else       run_layer<0, false>(x, nullptr, Wih0, Whh0, b0v, h1buf, slots, role, ng, b0r, Gs, tid);
  } else {
    if (local) run_layer<1, true >(nullptr, h1buf, Wih1, Whh1, b1v, h2buf, slots, role, ng, b0r, Gs, tid);
    else       run_layer<1, false>(nullptr, h1buf, Wih1, Whh1, b1v, h2buf, slots, role, ng, b0r, Gs, tid);
  }
}

// final dense (C=10) + softmax on h2[T-1]; one wave per batch row.
// (kernel-end release flushes dirty h lines; standard inter-kernel visibility.)
__global__ __launch_bounds__(64, 1) void dense_softmax_k(const f16* __restrict__ h2,
                                                         const float* __restrict__ Wd,
                                                         const float* __restrict__ bd,
                                                         float* __restrict__ out) {
  const int b = blockIdx.x, lane = threadIdx.x;
  float hv[4];
#pragma unroll
  for (int j = 0; j < 4; ++j) hv[j] = (float)h2[b * 256 + lane + 64 * j];
  float p[10];
#pragma unroll
  for (int c = 0; c < 10; ++c) {
    float s = 0.f;
#pragma unroll
    for (int j = 0; j < 4; ++j) s += hv[j] * Wd[c * 256 + lane + 64 * j];
#pragma unroll
    for (int off = 32; off >= 1; off >>= 1) s += __shfl_xor(s, off, 64);
    p[c] = s;
  }
  if (lane == 0) {
    float mx = -1e30f;
#pragma unroll
    for (int c = 0; c < 10; ++c) { p[c] += bd[c]; mx = fmaxf(mx, p[c]); }
    float den = 0.f;
#pragma unroll
    for (int c = 0; c < 10; ++c) { p[c] = __expf(p[c] - mx); den += p[c]; }
#pragma unroll
    for (int c = 0; c < 10; ++c) out[b * 10 + c] = p[c] / den;
  }
}

extern "C" void kernel_launch(void* const* d_in, const int* in_sizes, int n_in,
                              void* d_out, int out_size, void* d_ws, size_t ws_size,
                              hipStream_t stream) {
  const float* x    = (const float*)d_in[0];
  const float* Wih0 = (const float*)d_in[1];
  const float* Whh0 = (const float*)d_in[2];
  const float* b0v  = (const float*)d_in[3];
  const float* Wih1 = (const float*)d_in[4];
  const float* Whh1 = (const float*)d_in[5];
  const float* b1v  = (const float*)d_in[6];
  const float* Wd   = (const float*)d_in[7];
  const float* bd   = (const float*)d_in[8];

  char* ws = (char*)d_ws;
  // layout: h1buf[3] @0 (384KB) | h2buf[2] @384K (256KB) | slots+NG @640K (64KB)
  f16* h1buf = (f16*)(ws);
  f16* h2buf = (f16*)(ws + 384 * 1024);
  unsigned* F = (unsigned*)(ws + 640 * 1024);

  // zero h1 buffer 2 (initial h1[-1], @256K) + h2 buffer 0 (initial h2 state, @384K)
  // -> contiguous 256KB; and all slots/NG.
  hipMemsetAsync(ws + 256 * 1024, 0, 256 * 1024, stream);
  hipMemsetAsync(ws + 640 * 1024, 0, 64 * 1024, stream);

  lstm_persistent<<<256, 256, 0, stream>>>(x, Wih0, Whh0, b0v, Wih1, Whh1, b1v,
                                           h1buf, h2buf, F);
  // h2[T-1] lands in h2buf[0] (T even)
  dense_softmax_k<<<256, 64, 0, stream>>>(h2buf, Wd, bd, (float*)d_out);
}